// Round 1
// baseline (5145.429 us; speedup 1.0000x reference)
//
#include <hip/hip_runtime.h>
#include <math.h>

#define NN   100000
#define EE   1000000
#define CCH  256      // context channels
#define DMC  128      // stage_metrics channels
#define HDC  192      // hidden of final transform
#define OUTC 128      // out channels

__device__ __forceinline__ float selu_f(float x) {
    const float sc = 1.0507009873554804934193349852946f;
    const float al = 1.6732632423543772848170429916717f;
    return x > 0.0f ? sc * x : sc * al * expm1f(x);
}

// ---------------- K1: node transform  cl = nc@W_l+b_l, cr = nc@W_r+b_r ----
// 32 nodes per block, 256 threads; thread owns one output column for both mats.
__global__ __launch_bounds__(256) void k_node_transform(
    const float* __restrict__ ss, const float* __restrict__ se,
    const float* __restrict__ ctx, const float* __restrict__ Wl,
    const float* __restrict__ bl, const float* __restrict__ Wr,
    const float* __restrict__ br, float* __restrict__ cl,
    float* __restrict__ cr)
{
    __shared__ float ncs[32][CCH];  // 32 KB; reads below are wave-broadcast (no conflicts)
    const int tid = threadIdx.x;
    const int node0 = blockIdx.x * 32;

    for (int k = tid; k < 32 * CCH; k += 256) {
        const int t = k >> 8, c = k & 255;
        const int n = node0 + t;
        float v;
        if (c < 16)       v = ss[n * 16 + c];
        else if (c < 240) v = ctx[n * 224 + (c - 16)];
        else              v = se[n * 16 + (c - 240)];
        ncs[t][c] = v;
    }
    __syncthreads();

    const int o = tid;
    float accL[32], accR[32];
#pragma unroll
    for (int t = 0; t < 32; ++t) { accL[t] = 0.f; accR[t] = 0.f; }

    for (int c4 = 0; c4 < CCH / 4; ++c4) {
        const float wl0 = Wl[(c4 * 4 + 0) * CCH + o];
        const float wl1 = Wl[(c4 * 4 + 1) * CCH + o];
        const float wl2 = Wl[(c4 * 4 + 2) * CCH + o];
        const float wl3 = Wl[(c4 * 4 + 3) * CCH + o];
        const float wr0 = Wr[(c4 * 4 + 0) * CCH + o];
        const float wr1 = Wr[(c4 * 4 + 1) * CCH + o];
        const float wr2 = Wr[(c4 * 4 + 2) * CCH + o];
        const float wr3 = Wr[(c4 * 4 + 3) * CCH + o];
#pragma unroll
        for (int t = 0; t < 32; ++t) {
            const float4 v = *reinterpret_cast<const float4*>(&ncs[t][c4 * 4]);
            accL[t] += v.x * wl0 + v.y * wl1 + v.z * wl2 + v.w * wl3;
            accR[t] += v.x * wr0 + v.y * wr1 + v.z * wr2 + v.w * wr3;
        }
    }

#pragma unroll
    for (int t = 0; t < 32; ++t) {
        const int n = node0 + t;
        cl[(size_t)n * CCH + o] = accL[t] + bl[o];
        cr[(size_t)n * CCH + o] = accR[t] + br[o];
    }
}

// ---------------- K2: per-edge alpha, ex, segment-sum s ------------------
// One wave per edge. exb[e] = mask ? exp(alpha) : 0 ; sb[dst] += ex.
__global__ __launch_bounds__(256) void k_edge_alpha(
    const int* __restrict__ ei, const float* __restrict__ cl,
    const float* __restrict__ cr, const float* __restrict__ met,
    const float* __restrict__ att, float* __restrict__ exb,
    float* __restrict__ sb)
{
    const int lane = threadIdx.x & 63;
    const int eid = blockIdx.x * 4 + (threadIdx.x >> 6);
    const int src = ei[eid];
    const int dst = ei[EE + eid];

    const float4 vr = *reinterpret_cast<const float4*>(&cr[(size_t)dst * CCH + lane * 4]);
    const float4 vl = *reinterpret_cast<const float4*>(&cl[(size_t)src * CCH + lane * 4]);
    const float4 av = *reinterpret_cast<const float4*>(&att[lane * 4]);

    float p = selu_f(vr.x + vl.x) * av.x + selu_f(vr.y + vl.y) * av.y +
              selu_f(vr.z + vl.z) * av.z + selu_f(vr.w + vl.w) * av.w;

    const float m0 = met[(size_t)src * DMC + lane];
    const float m1 = met[(size_t)src * DMC + 64 + lane];
    const bool allz = __all((m0 == 0.f) && (m1 == 0.f));

#pragma unroll
    for (int off = 32; off; off >>= 1) p += __shfl_xor(p, off);

    const float alpha = allz ? 0.f : p;
    const float ex = (alpha != 0.f) ? expf(alpha) : 0.f;
    if (lane == 0) {
        exb[eid] = ex;
        if (ex != 0.f) atomicAdd(&sb[dst], ex);
    }
}

// ---------------- K3: per-edge 2-layer MLP + weighted scatter-add --------
// 32 edges per block, 256 threads. Register-blocked fp32 GEMM:
// thread = (eg 0..7, og 0..31); GEMM1: 4 edges x 6 cols; GEMM2: 4 edges x 4 cols.
// X row padded to 388 floats (388 % 32 == 4) to de-conflict LDS banks.
__global__ __launch_bounds__(256) void k_edge_mlp(
    const int* __restrict__ ei, const float* __restrict__ cl,
    const float* __restrict__ cr, const float* __restrict__ met,
    const float* __restrict__ exb, const float* __restrict__ sb,
    const float* __restrict__ W1, const float* __restrict__ b1,
    const float* __restrict__ W2, const float* __restrict__ b2,
    float* __restrict__ dout)
{
    __shared__ float X[32][388];         // also reused to hold H (cols 0..191)
    __shared__ int esrc[32], edst[32];
    __shared__ float aa[32];

    const int tid = threadIdx.x;
    const int ebase = blockIdx.x * 32;

    if (tid < 32) {
        const int eg = ebase + tid;
        const int s_ = ei[eg];
        const int d_ = ei[EE + eg];
        esrc[tid] = s_;
        edst[tid] = d_;
        const float ex = exb[eg];
        aa[tid] = (ex != 0.f) ? ex / (sb[d_] + 1e-16f) : 0.f;
    }
    __syncthreads();

    // build X = [selu(cr[dst]+cl[src]) | metrics[src]]  (32 x 384)
    for (int k = tid; k < 32 * 384; k += 256) {
        const int t = k / 384, c = k - t * 384;
        float v;
        if (c < 256)
            v = selu_f(cr[(size_t)edst[t] * CCH + c] + cl[(size_t)esrc[t] * CCH + c]);
        else
            v = met[(size_t)esrc[t] * DMC + (c - 256)];
        X[t][c] = v;
    }
    __syncthreads();

    const int eg = tid >> 5;     // 0..7
    const int og = tid & 31;     // 0..31

    // GEMM1: H = selu(X @ W1 + b1)   [32 x 192]
    float acc1[4][6];
#pragma unroll
    for (int k = 0; k < 4; ++k)
#pragma unroll
        for (int j = 0; j < 6; ++j) acc1[k][j] = 0.f;

    for (int c4 = 0; c4 < 96; ++c4) {
        float4 xv[4];
#pragma unroll
        for (int k = 0; k < 4; ++k)
            xv[k] = *reinterpret_cast<const float4*>(&X[eg + 8 * k][c4 * 4]);
#pragma unroll
        for (int j = 0; j < 6; ++j) {
            const int o = og + 32 * j;
            const float w0 = W1[(4 * c4 + 0) * HDC + o];
            const float w1 = W1[(4 * c4 + 1) * HDC + o];
            const float w2 = W1[(4 * c4 + 2) * HDC + o];
            const float w3 = W1[(4 * c4 + 3) * HDC + o];
#pragma unroll
            for (int k = 0; k < 4; ++k)
                acc1[k][j] += xv[k].x * w0 + xv[k].y * w1 + xv[k].z * w2 + xv[k].w * w3;
        }
    }

    __syncthreads();  // all GEMM1 reads of X complete before overwrite
#pragma unroll
    for (int j = 0; j < 6; ++j) {
        const int o = og + 32 * j;
        const float bb = b1[o];
#pragma unroll
        for (int k = 0; k < 4; ++k)
            X[eg + 8 * k][o] = selu_f(acc1[k][j] + bb);
    }
    __syncthreads();

    // GEMM2: F = selu(H @ W2 + b2)   [32 x 128], then scatter F * a
    float acc2[4][4];
#pragma unroll
    for (int k = 0; k < 4; ++k)
#pragma unroll
        for (int j = 0; j < 4; ++j) acc2[k][j] = 0.f;

    for (int c4 = 0; c4 < 48; ++c4) {
        float4 xv[4];
#pragma unroll
        for (int k = 0; k < 4; ++k)
            xv[k] = *reinterpret_cast<const float4*>(&X[eg + 8 * k][c4 * 4]);
#pragma unroll
        for (int j = 0; j < 4; ++j) {
            const int o = og + 32 * j;
            const float w0 = W2[(4 * c4 + 0) * OUTC + o];
            const float w1 = W2[(4 * c4 + 1) * OUTC + o];
            const float w2 = W2[(4 * c4 + 2) * OUTC + o];
            const float w3 = W2[(4 * c4 + 3) * OUTC + o];
#pragma unroll
            for (int k = 0; k < 4; ++k)
                acc2[k][j] += xv[k].x * w0 + xv[k].y * w1 + xv[k].z * w2 + xv[k].w * w3;
        }
    }

#pragma unroll
    for (int k = 0; k < 4; ++k) {
        const int e = eg + 8 * k;
        const float a = aa[e];
        if (a != 0.f) {
            const int d = edst[e];
#pragma unroll
            for (int j = 0; j < 4; ++j) {
                const int o = og + 32 * j;
                const float f = selu_f(acc2[k][j] + b2[o]);
                atomicAdd(&dout[(size_t)d * OUTC + o], f * a);
            }
        }
    }
}

// ---------------- K4: finalize (overwrite-or-sigmoid), in place ----------
__global__ __launch_bounds__(64) void k_finalize(
    float* __restrict__ dout, const float* __restrict__ met,
    const float* __restrict__ bias)
{
    const int n = blockIdx.x;
    const int lane = threadIdx.x;
    const float a0 = dout[(size_t)n * OUTC + lane];
    const float a1 = dout[(size_t)n * OUTC + 64 + lane];
    const bool ovr = __all((a0 == 0.f) && (a1 == 0.f));
    float r0, r1;
    if (ovr) {
        r0 = met[(size_t)n * DMC + lane];
        r1 = met[(size_t)n * DMC + 64 + lane];
    } else {
        r0 = 1.f / (1.f + expf(-(a0 + bias[lane])));
        r1 = 1.f / (1.f + expf(-(a1 + bias[64 + lane])));
    }
    dout[(size_t)n * OUTC + lane] = r0;
    dout[(size_t)n * OUTC + 64 + lane] = r1;
}

extern "C" void kernel_launch(void* const* d_in, const int* in_sizes, int n_in,
                              void* d_out, int out_size, void* d_ws, size_t ws_size,
                              hipStream_t stream)
{
    const int*   ei   = (const int*)d_in[0];
    const float* ss   = (const float*)d_in[1];
    const float* se   = (const float*)d_in[2];
    const float* ctx  = (const float*)d_in[3];
    const float* met  = (const float*)d_in[4];
    const float* Wl   = (const float*)d_in[5];
    const float* bl   = (const float*)d_in[6];
    const float* Wr   = (const float*)d_in[7];
    const float* br   = (const float*)d_in[8];
    const float* att  = (const float*)d_in[9];
    const float* W1   = (const float*)d_in[10];
    const float* b1   = (const float*)d_in[11];
    const float* W2   = (const float*)d_in[12];
    const float* b2   = (const float*)d_in[13];
    const float* bias = (const float*)d_in[14];

    float* ws  = (float*)d_ws;
    float* cl  = ws;                              // N*256 floats
    float* cr  = ws + (size_t)NN * CCH;           // N*256 floats
    float* exb = ws + 2 * (size_t)NN * CCH;       // E floats
    float* sb  = exb + EE;                        // N floats

    float* dout = (float*)d_out;

    hipMemsetAsync(dout, 0, (size_t)NN * OUTC * sizeof(float), stream);
    hipMemsetAsync(sb, 0, (size_t)NN * sizeof(float), stream);

    k_node_transform<<<NN / 32, 256, 0, stream>>>(ss, se, ctx, Wl, bl, Wr, br, cl, cr);
    k_edge_alpha<<<EE / 4, 256, 0, stream>>>(ei, cl, cr, met, att, exb, sb);
    k_edge_mlp<<<EE / 32, 256, 0, stream>>>(ei, cl, cr, met, exb, sb, W1, b1, W2, b2, dout);
    k_finalize<<<NN, 64, 0, stream>>>(dout, met, bias);
}

// Round 2
// 1800.154 us; speedup vs baseline: 2.8583x; 2.8583x over previous
//
#include <hip/hip_runtime.h>
#include <math.h>

#define NN   100000
#define EE   1000000
#define CCH  256      // context channels
#define DMC  128      // stage_metrics channels
#define HDC  192      // hidden of final transform
#define OUTC 128      // out channels

typedef unsigned short u16;
using bf16x8 = __attribute__((ext_vector_type(8))) short;
using f32x4  = __attribute__((ext_vector_type(4))) float;
using u16x2  = __attribute__((ext_vector_type(2))) unsigned short;
using u16x4  = __attribute__((ext_vector_type(4))) unsigned short;
using u16x8  = __attribute__((ext_vector_type(8))) unsigned short;

__device__ __forceinline__ float selu_f(float x) {
    const float sc = 1.0507009873554804934193349852946f;
    const float al = 1.6732632423543772848170429916717f;
    return x > 0.0f ? sc * x : sc * al * expm1f(x);
}
__device__ __forceinline__ u16 f2bf(float f) {          // round-to-nearest-even
    unsigned int u = __float_as_uint(f);
    u += 0x7fffu + ((u >> 16) & 1u);
    return (u16)(u >> 16);
}
__device__ __forceinline__ float bf2f(u16 h) {
    return __uint_as_float(((unsigned int)h) << 16);
}

// ---------------- K1: node transform -> bf16 cl, cr ----------------------
__global__ __launch_bounds__(256) void k_node_transform(
    const float* __restrict__ ss, const float* __restrict__ se,
    const float* __restrict__ ctx, const float* __restrict__ Wl,
    const float* __restrict__ bl, const float* __restrict__ Wr,
    const float* __restrict__ br, u16* __restrict__ clb,
    u16* __restrict__ crb)
{
    __shared__ float ncs[32][CCH];
    const int tid = threadIdx.x;
    const int node0 = blockIdx.x * 32;

    for (int k = tid; k < 32 * CCH; k += 256) {
        const int t = k >> 8, c = k & 255;
        const int n = node0 + t;
        float v;
        if (c < 16)       v = ss[n * 16 + c];
        else if (c < 240) v = ctx[n * 224 + (c - 16)];
        else              v = se[n * 16 + (c - 240)];
        ncs[t][c] = v;
    }
    __syncthreads();

    const int o = tid;
    float accL[32], accR[32];
#pragma unroll
    for (int t = 0; t < 32; ++t) { accL[t] = 0.f; accR[t] = 0.f; }

    for (int c4 = 0; c4 < CCH / 4; ++c4) {
        const float wl0 = Wl[(c4 * 4 + 0) * CCH + o];
        const float wl1 = Wl[(c4 * 4 + 1) * CCH + o];
        const float wl2 = Wl[(c4 * 4 + 2) * CCH + o];
        const float wl3 = Wl[(c4 * 4 + 3) * CCH + o];
        const float wr0 = Wr[(c4 * 4 + 0) * CCH + o];
        const float wr1 = Wr[(c4 * 4 + 1) * CCH + o];
        const float wr2 = Wr[(c4 * 4 + 2) * CCH + o];
        const float wr3 = Wr[(c4 * 4 + 3) * CCH + o];
#pragma unroll
        for (int t = 0; t < 32; ++t) {
            const float4 v = *reinterpret_cast<const float4*>(&ncs[t][c4 * 4]);
            accL[t] += v.x * wl0 + v.y * wl1 + v.z * wl2 + v.w * wl3;
            accR[t] += v.x * wr0 + v.y * wr1 + v.z * wr2 + v.w * wr3;
        }
    }

#pragma unroll
    for (int t = 0; t < 32; ++t) {
        const int n = node0 + t;
        clb[(size_t)n * CCH + o] = f2bf(accL[t] + bl[o]);
        crb[(size_t)n * CCH + o] = f2bf(accR[t] + br[o]);
    }
}

// ---------------- K1b: fp32 -> bf16 convert (for metrics) ----------------
__global__ __launch_bounds__(256) void k_convert(
    const float* __restrict__ in, u16* __restrict__ out, int n)
{
    const int i = (blockIdx.x * 256 + threadIdx.x) * 4;
    if (i < n) {
        const float4 v = *reinterpret_cast<const float4*>(in + i);
        u16x4 o; o[0] = f2bf(v.x); o[1] = f2bf(v.y); o[2] = f2bf(v.z); o[3] = f2bf(v.w);
        *reinterpret_cast<u16x4*>(out + i) = o;
    }
}

// ---------------- K1c: pack W (KxN fp32 row-major) into MFMA B-fragments -
// frag f = nt*(K/32) + ks ; lane l holds B[k0+(l>>4)*8 + j][nt*16 + (l&15)],
// j=0..7, contiguous 16B per lane -> coalesced dwordx4 loads in the GEMM.
__global__ __launch_bounds__(64) void k_pack_w(
    const float* __restrict__ W, u16* __restrict__ out, int K, int N)
{
    const int f = blockIdx.x, lane = threadIdx.x;
    const int KS = K >> 5;
    const int nt = f / KS, ks = f - nt * KS;
    const int n = nt * 16 + (lane & 15);
    const int k0 = ks * 32 + (lane >> 4) * 8;
    u16x8 v;
#pragma unroll
    for (int j = 0; j < 8; ++j) v[j] = f2bf(W[(size_t)(k0 + j) * N + n]);
    *reinterpret_cast<u16x8*>(out + ((size_t)f * 64 + lane) * 8) = v;
}

// ---------------- K2: per-edge alpha, ex, segment-sum s ------------------
__global__ __launch_bounds__(256) void k_edge_alpha(
    const int* __restrict__ ei, const u16* __restrict__ clb,
    const u16* __restrict__ crb, const u16* __restrict__ metb,
    const float* __restrict__ att, float* __restrict__ exb,
    float* __restrict__ sb)
{
    const int lane = threadIdx.x & 63;
    const int eid = blockIdx.x * 4 + (threadIdx.x >> 6);
    const int src = ei[eid];
    const int dst = ei[EE + eid];

    const u16x4 r = *reinterpret_cast<const u16x4*>(crb + (size_t)dst * CCH + lane * 4);
    const u16x4 l = *reinterpret_cast<const u16x4*>(clb + (size_t)src * CCH + lane * 4);
    const float4 av = *reinterpret_cast<const float4*>(att + lane * 4);

    float p = selu_f(bf2f(r[0]) + bf2f(l[0])) * av.x
            + selu_f(bf2f(r[1]) + bf2f(l[1])) * av.y
            + selu_f(bf2f(r[2]) + bf2f(l[2])) * av.z
            + selu_f(bf2f(r[3]) + bf2f(l[3])) * av.w;

    const u16x2 mm = *reinterpret_cast<const u16x2*>(metb + (size_t)src * DMC + lane * 2);
    const bool allz = __all((((unsigned)mm[0] | (unsigned)mm[1]) & 0x7fffu) == 0u);

#pragma unroll
    for (int off = 32; off; off >>= 1) p += __shfl_xor(p, off);

    const float alpha = allz ? 0.f : p;
    const float ex = (alpha != 0.f) ? expf(alpha) : 0.f;
    if (lane == 0) {
        exb[eid] = ex;
        if (ex != 0.f) atomicAdd(&sb[dst], ex);
    }
}

// ---------------- K3: per-edge MLP via bf16 MFMA + weighted scatter ------
// 64 edges/block, 4 waves. mfma_f32_16x16x32_bf16.
// GEMM1: [64x384]@[384x192]; wave w owns n-tiles {w,w+4,w+8}, all 4 m-tiles.
// GEMM2: [64x192]@[192x128]; wave w owns n-tiles {w,w+4}.
// X/H in one 48KB LDS buffer; XOR swizzle byte^=((row&7)<<4) kills the
// 16-way bank conflict of row-stride 768B/384B (both ==0 mod 128).
__global__ __launch_bounds__(256, 3) void k_edge_mlp(
    const int* __restrict__ ei, const u16* __restrict__ clb,
    const u16* __restrict__ crb, const u16* __restrict__ metb,
    const float* __restrict__ exb, const float* __restrict__ sb,
    const u16* __restrict__ W1p, const float* __restrict__ b1,
    const u16* __restrict__ W2p, const float* __restrict__ b2,
    float* __restrict__ dout)
{
    __shared__ __align__(16) char Xs[64 * 768];   // X: [64][384]bf16; reused for H [64][192]bf16
    __shared__ int esrc[64], edst[64];
    __shared__ float aa[64];

    const int tid  = threadIdx.x;
    const int wave = tid >> 6;
    const int lane = tid & 63;
    const int ebase = blockIdx.x * 64;

    if (tid < 64) {
        const int e = ebase + tid;
        const int s_ = ei[e], d_ = ei[EE + e];
        esrc[tid] = s_; edst[tid] = d_;
        const float ex = exb[e];
        aa[tid] = (ex != 0.f) ? ex / (sb[d_] + 1e-16f) : 0.f;
    }
    __syncthreads();

    // ---- build X = [selu(cr[dst]+cl[src]) | metrics[src]] as bf16, swizzled
    for (int k = tid; k < 64 * 48; k += 256) {
        const int t = k / 48, c = k - t * 48;   // c: group of 8 cols
        u16x8 v;
        if (c < 32) {
            const u16x8 r = *reinterpret_cast<const u16x8*>(crb + (size_t)edst[t] * CCH + c * 8);
            const u16x8 l = *reinterpret_cast<const u16x8*>(clb + (size_t)esrc[t] * CCH + c * 8);
#pragma unroll
            for (int j = 0; j < 8; ++j) v[j] = f2bf(selu_f(bf2f(r[j]) + bf2f(l[j])));
        } else {
            v = *reinterpret_cast<const u16x8*>(metb + (size_t)esrc[t] * DMC + (c - 32) * 8);
        }
        *reinterpret_cast<u16x8*>(Xs + t * 768 + ((c * 16) ^ ((t & 7) << 4))) = v;
    }
    __syncthreads();

    const int r16   = lane & 15;
    const int khalf = (lane >> 4) << 4;   // byte offset of this lane's 8-elem k-run
    const int rbase = (lane >> 4) * 4;

    // ---- GEMM1: H = selu(X @ W1 + b1), accumulate in registers
    f32x4 acc[4][3];
#pragma unroll
    for (int m = 0; m < 4; ++m)
#pragma unroll
        for (int j = 0; j < 3; ++j) acc[m][j] = (f32x4){0.f, 0.f, 0.f, 0.f};

    for (int ks = 0; ks < 12; ++ks) {
        bf16x8 b[3];
#pragma unroll
        for (int j = 0; j < 3; ++j)
            b[j] = *reinterpret_cast<const bf16x8*>(
                W1p + (((size_t)(wave + 4 * j) * 12 + ks) * 64 + lane) * 8);
        const int kb = ks * 64 + khalf;
#pragma unroll
        for (int m = 0; m < 4; ++m) {
            const int row = m * 16 + r16;
            const bf16x8 a = *reinterpret_cast<const bf16x8*>(
                Xs + row * 768 + (kb ^ ((row & 7) << 4)));
#pragma unroll
            for (int j = 0; j < 3; ++j)
                acc[m][j] = __builtin_amdgcn_mfma_f32_16x16x32_bf16(a, b[j], acc[m][j], 0, 0, 0);
        }
    }
    __syncthreads();   // all X reads complete before overwrite with H

    // ---- write H (bf16, swizzled, row stride 384B) into Xs
#pragma unroll
    for (int j = 0; j < 3; ++j) {
        const int n = (wave + 4 * j) * 16 + r16;
        const float bb = b1[n];
#pragma unroll
        for (int m = 0; m < 4; ++m)
#pragma unroll
            for (int r = 0; r < 4; ++r) {
                const int row = m * 16 + rbase + r;
                *reinterpret_cast<u16*>(Xs + row * 384 + ((n * 2) ^ ((row & 7) << 4))) =
                    f2bf(selu_f(acc[m][j][r] + bb));
            }
    }
    __syncthreads();

    // ---- GEMM2: F = selu(H @ W2 + b2)
    f32x4 acc2[4][2];
#pragma unroll
    for (int m = 0; m < 4; ++m)
#pragma unroll
        for (int j = 0; j < 2; ++j) acc2[m][j] = (f32x4){0.f, 0.f, 0.f, 0.f};

    for (int ks = 0; ks < 6; ++ks) {
        bf16x8 b[2];
#pragma unroll
        for (int j = 0; j < 2; ++j)
            b[j] = *reinterpret_cast<const bf16x8*>(
                W2p + (((size_t)(wave + 4 * j) * 6 + ks) * 64 + lane) * 8);
        const int kb = ks * 64 + khalf;
#pragma unroll
        for (int m = 0; m < 4; ++m) {
            const int row = m * 16 + r16;
            const bf16x8 a = *reinterpret_cast<const bf16x8*>(
                Xs + row * 384 + (kb ^ ((row & 7) << 4)));
#pragma unroll
            for (int j = 0; j < 2; ++j)
                acc2[m][j] = __builtin_amdgcn_mfma_f32_16x16x32_bf16(a, b[j], acc2[m][j], 0, 0, 0);
        }
    }

    // ---- epilogue: msg = selu(F)*a, scatter-add by dst
#pragma unroll
    for (int j = 0; j < 2; ++j) {
        const int n = (wave + 4 * j) * 16 + r16;
        const float bb = b2[n];
#pragma unroll
        for (int m = 0; m < 4; ++m)
#pragma unroll
            for (int r = 0; r < 4; ++r) {
                const int e = m * 16 + rbase + r;
                const float a_ = aa[e];
                if (a_ != 0.f)
                    atomicAdd(&dout[(size_t)edst[e] * OUTC + n],
                              selu_f(acc2[m][j][r] + bb) * a_);
            }
    }
}

// ---------------- K4: finalize (overwrite-or-sigmoid), in place ----------
__global__ __launch_bounds__(64) void k_finalize(
    float* __restrict__ dout, const float* __restrict__ met,
    const float* __restrict__ bias)
{
    const int n = blockIdx.x;
    const int lane = threadIdx.x;
    const float a0 = dout[(size_t)n * OUTC + lane];
    const float a1 = dout[(size_t)n * OUTC + 64 + lane];
    const bool ovr = __all((a0 == 0.f) && (a1 == 0.f));
    float r0, r1;
    if (ovr) {
        r0 = met[(size_t)n * DMC + lane];
        r1 = met[(size_t)n * DMC + 64 + lane];
    } else {
        r0 = 1.f / (1.f + expf(-(a0 + bias[lane])));
        r1 = 1.f / (1.f + expf(-(a1 + bias[64 + lane])));
    }
    dout[(size_t)n * OUTC + lane] = r0;
    dout[(size_t)n * OUTC + 64 + lane] = r1;
}

extern "C" void kernel_launch(void* const* d_in, const int* in_sizes, int n_in,
                              void* d_out, int out_size, void* d_ws, size_t ws_size,
                              hipStream_t stream)
{
    const int*   ei   = (const int*)d_in[0];
    const float* ss   = (const float*)d_in[1];
    const float* se   = (const float*)d_in[2];
    const float* ctx  = (const float*)d_in[3];
    const float* met  = (const float*)d_in[4];
    const float* Wl   = (const float*)d_in[5];
    const float* bl   = (const float*)d_in[6];
    const float* Wr   = (const float*)d_in[7];
    const float* br   = (const float*)d_in[8];
    const float* att  = (const float*)d_in[9];
    const float* W1   = (const float*)d_in[10];
    const float* b1   = (const float*)d_in[11];
    const float* W2   = (const float*)d_in[12];
    const float* b2   = (const float*)d_in[13];
    const float* bias = (const float*)d_in[14];

    u16* clb  = (u16*)d_ws;
    u16* crb  = clb  + (size_t)NN * CCH;
    u16* metb = crb  + (size_t)NN * CCH;
    u16* W1p  = metb + (size_t)NN * DMC;
    u16* W2p  = W1p  + (size_t)(CCH + DMC) * HDC;
    float* exb = (float*)(W2p + (size_t)HDC * OUTC);
    float* sb  = exb + EE;

    float* dout = (float*)d_out;

    hipMemsetAsync(dout, 0, (size_t)NN * OUTC * sizeof(float), stream);
    hipMemsetAsync(sb, 0, (size_t)NN * sizeof(float), stream);

    k_node_transform<<<NN / 32, 256, 0, stream>>>(ss, se, ctx, Wl, bl, Wr, br, clb, crb);
    k_convert<<<(NN * DMC / 4 + 255) / 256, 256, 0, stream>>>(met, metb, NN * DMC);
    k_pack_w<<<(HDC / 16) * ((CCH + DMC) / 32), 64, 0, stream>>>(W1, W1p, CCH + DMC, HDC);
    k_pack_w<<<(OUTC / 16) * (HDC / 32), 64, 0, stream>>>(W2, W2p, HDC, OUTC);
    k_edge_alpha<<<EE / 4, 256, 0, stream>>>(ei, clb, crb, metb, att, exb, sb);
    k_edge_mlp<<<EE / 64, 256, 0, stream>>>(ei, clb, crb, metb, exb, sb, W1p, b1, W2p, b2, dout);
    k_finalize<<<NN, 64, 0, stream>>>(dout, met, bias);
}

// Round 3
// 1077.627 us; speedup vs baseline: 4.7748x; 1.6705x over previous
//
#include <hip/hip_runtime.h>
#include <hip/hip_bf16.h>
#include <math.h>

#define NN   100000
#define EE   1000000
#define CCH  256      // context channels
#define DMC  128      // stage_metrics channels
#define HDC  192      // hidden of final transform
#define OUTC 128      // out channels
#define ET   48       // edges per k_edge_mlp block (3 m-tiles)

typedef unsigned short u16;
using bf16x8 = __attribute__((ext_vector_type(8))) short;
using f32x4  = __attribute__((ext_vector_type(4))) float;
using u16x4  = __attribute__((ext_vector_type(4))) unsigned short;
using u16x8  = __attribute__((ext_vector_type(8))) unsigned short;

// selu via v_exp: ~6 VALU vs ~13 for expm1f path
__device__ __forceinline__ float selu_f(float x) {
    const float sc = 1.0507009873554804934193349852946f;
    const float c1 = 1.7580993408473765792727863477367f;  // sc*alpha
    const float e = __expf(x);
    return x > 0.0f ? sc * x : __builtin_fmaf(c1, e, -c1);
}
__device__ __forceinline__ u16 f2bf(float f) {   // RNE via compiler (emits cvt_pk)
    union { __hip_bfloat16 h; u16 u; } c;
    c.h = __float2bfloat16(f);
    return c.u;
}
__device__ __forceinline__ float bf2f(u16 h) {
    return __uint_as_float(((unsigned int)h) << 16);
}

// ---------------- K1: node transform as bf16 MFMA GEMM -------------------
// [64 nodes x 256] @ [256 x 512] (Wl|Wr fused). 4 waves; wave owns all 4
// m-tiles x 8 n-tiles (nt = wave+4*jj). X in LDS bf16, swizzled.
__global__ __launch_bounds__(256, 2) void k_node_gemm(
    const float* __restrict__ ss, const float* __restrict__ se,
    const float* __restrict__ ctx, const u16* __restrict__ W0p,
    const float* __restrict__ bl, const float* __restrict__ br,
    u16* __restrict__ clb, u16* __restrict__ crb)
{
    __shared__ __align__(16) char Xs[64 * 512];  // [64][256] bf16 swizzled
    const int tid = threadIdx.x;
    const int wave = tid >> 6, lane = tid & 63;
    const int node0 = blockIdx.x * 64;

    // stage: lane = row, wave = 64-col block; conflict-free swizzled writes
    {
        const int r = lane;
        const int nd = min(node0 + r, NN - 1);
#pragma unroll
        for (int i = 0; i < 8; ++i) {
            const int c0 = wave * 64 + i * 8;
            float4 va, vb;
            {
                const int c = c0;
                if (c < 16)       va = *reinterpret_cast<const float4*>(ss + nd * 16 + c);
                else if (c < 240) va = *reinterpret_cast<const float4*>(ctx + (size_t)nd * 224 + (c - 16));
                else              va = *reinterpret_cast<const float4*>(se + nd * 16 + (c - 240));
            }
            {
                const int c = c0 + 4;
                if (c < 16)       vb = *reinterpret_cast<const float4*>(ss + nd * 16 + c);
                else if (c < 240) vb = *reinterpret_cast<const float4*>(ctx + (size_t)nd * 224 + (c - 16));
                else              vb = *reinterpret_cast<const float4*>(se + nd * 16 + (c - 240));
            }
            u16x8 v;
            v[0] = f2bf(va.x); v[1] = f2bf(va.y); v[2] = f2bf(va.z); v[3] = f2bf(va.w);
            v[4] = f2bf(vb.x); v[5] = f2bf(vb.y); v[6] = f2bf(vb.z); v[7] = f2bf(vb.w);
            *reinterpret_cast<u16x8*>(Xs + r * 512 + ((c0 * 2) ^ ((r & 7) << 4))) = v;
        }
    }
    __syncthreads();

    const int r16   = lane & 15;
    const int khalf = (lane >> 4) << 4;
    const int rbase = (lane >> 4) * 4;

    f32x4 acc[4][8];
#pragma unroll
    for (int m = 0; m < 4; ++m)
#pragma unroll
        for (int jj = 0; jj < 8; ++jj) acc[m][jj] = (f32x4){0.f, 0.f, 0.f, 0.f};

    for (int ks = 0; ks < 8; ++ks) {
        bf16x8 b[8];
#pragma unroll
        for (int jj = 0; jj < 8; ++jj)
            b[jj] = *reinterpret_cast<const bf16x8*>(
                W0p + (((size_t)(wave + 4 * jj) * 8 + ks) * 64 + lane) * 8);
        const int kb = ks * 64 + khalf;
#pragma unroll
        for (int m = 0; m < 4; ++m) {
            const int row = m * 16 + r16;
            const bf16x8 a = *reinterpret_cast<const bf16x8*>(
                Xs + row * 512 + (kb ^ ((row & 7) << 4)));
#pragma unroll
            for (int jj = 0; jj < 8; ++jj)
                acc[m][jj] = __builtin_amdgcn_mfma_f32_16x16x32_bf16(a, b[jj], acc[m][jj], 0, 0, 0);
        }
    }

#pragma unroll
    for (int jj = 0; jj < 8; ++jj) {
        const int nt = wave + 4 * jj;            // wave-uniform branch
        const bool isL = nt < 16;
        const int ncl = (isL ? nt * 16 : (nt - 16) * 16) + r16;
        const float bias = isL ? bl[ncl] : br[ncl];
        u16* base = (isL ? clb : crb) + ncl;
#pragma unroll
        for (int m = 0; m < 4; ++m)
#pragma unroll
            for (int rr = 0; rr < 4; ++rr) {
                const int node = node0 + m * 16 + rbase + rr;
                if (node < NN)
                    base[(size_t)node * CCH] = f2bf(acc[m][jj][rr] + bias);
            }
    }
}

// ---------------- K1b: fp32 -> bf16 convert (for metrics) ----------------
__global__ __launch_bounds__(256) void k_convert(
    const float* __restrict__ in, u16* __restrict__ out, int n)
{
    const int i = (blockIdx.x * 256 + threadIdx.x) * 4;
    if (i < n) {
        const float4 v = *reinterpret_cast<const float4*>(in + i);
        u16x4 o; o[0] = f2bf(v.x); o[1] = f2bf(v.y); o[2] = f2bf(v.z); o[3] = f2bf(v.w);
        *reinterpret_cast<u16x4*>(out + i) = o;
    }
}

// ---------------- K1c: pack W (KxN fp32 row-major) into MFMA B-fragments -
__global__ __launch_bounds__(64) void k_pack_w(
    const float* __restrict__ W, u16* __restrict__ out, int K, int N)
{
    const int f = blockIdx.x, lane = threadIdx.x;
    const int KS = K >> 5;
    const int nt = f / KS, ks = f - nt * KS;
    const int n = nt * 16 + (lane & 15);
    const int k0 = ks * 32 + (lane >> 4) * 8;
    u16x8 v;
#pragma unroll
    for (int j = 0; j < 8; ++j) v[j] = f2bf(W[(size_t)(k0 + j) * N + n]);
    *reinterpret_cast<u16x8*>(out + ((size_t)f * 64 + lane) * 8) = v;
}

// ---------------- K2: per-edge alpha, ex, segment-sum s ------------------
// 4 edges per wave (16 lanes each), u16x8 gathers (coalesced 512B/group).
__global__ __launch_bounds__(256) void k_edge_alpha(
    const int* __restrict__ ei, const u16* __restrict__ clb,
    const u16* __restrict__ crb, const u16* __restrict__ metb,
    const float* __restrict__ att, float* __restrict__ exb,
    float* __restrict__ sb)
{
    const int tid = threadIdx.x;
    const int lane = tid & 63;
    const int g = lane >> 4, li = lane & 15;
    const int eid = blockIdx.x * 16 + (tid >> 6) * 4 + g;
    const int src = ei[eid], dst = ei[EE + eid];

    const u16x8 r0 = *reinterpret_cast<const u16x8*>(crb + (size_t)dst * CCH + li * 16);
    const u16x8 r1 = *reinterpret_cast<const u16x8*>(crb + (size_t)dst * CCH + li * 16 + 8);
    const u16x8 l0 = *reinterpret_cast<const u16x8*>(clb + (size_t)src * CCH + li * 16);
    const u16x8 l1 = *reinterpret_cast<const u16x8*>(clb + (size_t)src * CCH + li * 16 + 8);
    const float4 a0 = *reinterpret_cast<const float4*>(att + li * 16);
    const float4 a1 = *reinterpret_cast<const float4*>(att + li * 16 + 4);
    const float4 a2 = *reinterpret_cast<const float4*>(att + li * 16 + 8);
    const float4 a3 = *reinterpret_cast<const float4*>(att + li * 16 + 12);

    float p;
    p  = selu_f(bf2f(r0[0]) + bf2f(l0[0])) * a0.x;
    p += selu_f(bf2f(r0[1]) + bf2f(l0[1])) * a0.y;
    p += selu_f(bf2f(r0[2]) + bf2f(l0[2])) * a0.z;
    p += selu_f(bf2f(r0[3]) + bf2f(l0[3])) * a0.w;
    p += selu_f(bf2f(r0[4]) + bf2f(l0[4])) * a1.x;
    p += selu_f(bf2f(r0[5]) + bf2f(l0[5])) * a1.y;
    p += selu_f(bf2f(r0[6]) + bf2f(l0[6])) * a1.z;
    p += selu_f(bf2f(r0[7]) + bf2f(l0[7])) * a1.w;
    p += selu_f(bf2f(r1[0]) + bf2f(l1[0])) * a2.x;
    p += selu_f(bf2f(r1[1]) + bf2f(l1[1])) * a2.y;
    p += selu_f(bf2f(r1[2]) + bf2f(l1[2])) * a2.z;
    p += selu_f(bf2f(r1[3]) + bf2f(l1[3])) * a2.w;
    p += selu_f(bf2f(r1[4]) + bf2f(l1[4])) * a3.x;
    p += selu_f(bf2f(r1[5]) + bf2f(l1[5])) * a3.y;
    p += selu_f(bf2f(r1[6]) + bf2f(l1[6])) * a3.z;
    p += selu_f(bf2f(r1[7]) + bf2f(l1[7])) * a3.w;

    const u16x8 mm = *reinterpret_cast<const u16x8*>(metb + (size_t)src * DMC + li * 8);
    unsigned ob = 0;
#pragma unroll
    for (int j = 0; j < 8; ++j) ob |= (unsigned)mm[j];
    const bool z = (ob & 0x7fffu) == 0u;          // this lane's 8 metrics all zero
    const unsigned long long bal = __ballot(z);
    const bool allz = ((bal >> (g * 16)) & 0xFFFFull) == 0xFFFFull;

#pragma unroll
    for (int off = 8; off; off >>= 1) p += __shfl_xor(p, off);

    const float alpha = allz ? 0.f : p;
    const float ex = (alpha != 0.f) ? __expf(alpha) : 0.f;
    if (li == 0) {
        exb[eid] = ex;
        if (ex != 0.f) atomicAdd(&sb[dst], ex);
    }
}

// ---------------- K3: per-edge MLP via bf16 MFMA + weighted scatter ------
// 48 edges/block (36.8KB LDS -> 4 blocks/CU), 4 waves.
// GEMM1: [48x384]@[384x192], wave owns 3 m x 3 n tiles.
// GEMM2: [48x192]@[192x128], wave owns 3 m x 2 n tiles.
__global__ __launch_bounds__(256, 4) void k_edge_mlp(
    const int* __restrict__ ei, const u16* __restrict__ clb,
    const u16* __restrict__ crb, const u16* __restrict__ metb,
    const float* __restrict__ exb, const float* __restrict__ sb,
    const u16* __restrict__ W1p, const float* __restrict__ b1,
    const u16* __restrict__ W2p, const float* __restrict__ b2,
    float* __restrict__ dout)
{
    __shared__ __align__(16) char Xs[ET * 768];   // X [48][384]bf16; reused for H [48][192]
    __shared__ int esrc[ET], edst[ET];
    __shared__ float aa[ET];

    const int tid  = threadIdx.x;
    const int wave = tid >> 6;
    const int lane = tid & 63;
    const int ebase = blockIdx.x * ET;

    if (tid < ET) {
        const int e = ebase + tid;
        const bool valid = e < EE;
        const int s_ = valid ? ei[e] : 0;
        const int d_ = valid ? ei[EE + e] : 0;
        esrc[tid] = s_; edst[tid] = d_;
        float a_ = 0.f;
        if (valid) {
            const float ex = exb[e];
            if (ex != 0.f) a_ = ex / (sb[d_] + 1e-16f);
        }
        aa[tid] = a_;
    }
    __syncthreads();

    // build X = [selu(cr[dst]+cl[src]) | metrics[src]], bf16, swizzled
    for (int k = tid; k < ET * 48; k += 256) {
        const int t = k / 48, c = k - t * 48;     // c: group of 8 cols
        u16x8 v;
        if (c < 32) {
            const u16x8 r = *reinterpret_cast<const u16x8*>(crb + (size_t)edst[t] * CCH + c * 8);
            const u16x8 l = *reinterpret_cast<const u16x8*>(clb + (size_t)esrc[t] * CCH + c * 8);
#pragma unroll
            for (int j = 0; j < 8; ++j) v[j] = f2bf(selu_f(bf2f(r[j]) + bf2f(l[j])));
        } else {
            v = *reinterpret_cast<const u16x8*>(metb + (size_t)esrc[t] * DMC + (c - 32) * 8);
        }
        *reinterpret_cast<u16x8*>(Xs + t * 768 + ((c * 16) ^ ((t & 7) << 4))) = v;
    }
    __syncthreads();

    const int r16   = lane & 15;
    const int khalf = (lane >> 4) << 4;
    const int rbase = (lane >> 4) * 4;

    // GEMM1: H = selu(X @ W1 + b1)
    f32x4 acc[3][3];
#pragma unroll
    for (int m = 0; m < 3; ++m)
#pragma unroll
        for (int j = 0; j < 3; ++j) acc[m][j] = (f32x4){0.f, 0.f, 0.f, 0.f};

    for (int ks = 0; ks < 12; ++ks) {
        bf16x8 b[3];
#pragma unroll
        for (int j = 0; j < 3; ++j)
            b[j] = *reinterpret_cast<const bf16x8*>(
                W1p + (((size_t)(wave + 4 * j) * 12 + ks) * 64 + lane) * 8);
        const int kb = ks * 64 + khalf;
#pragma unroll
        for (int m = 0; m < 3; ++m) {
            const int row = m * 16 + r16;
            const bf16x8 a = *reinterpret_cast<const bf16x8*>(
                Xs + row * 768 + (kb ^ ((row & 7) << 4)));
#pragma unroll
            for (int j = 0; j < 3; ++j)
                acc[m][j] = __builtin_amdgcn_mfma_f32_16x16x32_bf16(a, b[j], acc[m][j], 0, 0, 0);
        }
    }
    __syncthreads();   // all X reads complete before overwrite with H

    // write H (bf16, swizzled, row stride 384B)
#pragma unroll
    for (int j = 0; j < 3; ++j) {
        const int n = (wave + 4 * j) * 16 + r16;
        const float bb = b1[n];
#pragma unroll
        for (int m = 0; m < 3; ++m)
#pragma unroll
            for (int r = 0; r < 4; ++r) {
                const int row = m * 16 + rbase + r;
                *reinterpret_cast<u16*>(Xs + row * 384 + ((n * 2) ^ ((row & 7) << 4))) =
                    f2bf(selu_f(acc[m][j][r] + bb));
            }
    }
    __syncthreads();

    // GEMM2: F = selu(H @ W2 + b2)
    f32x4 acc2[3][2];
#pragma unroll
    for (int m = 0; m < 3; ++m)
#pragma unroll
        for (int j = 0; j < 2; ++j) acc2[m][j] = (f32x4){0.f, 0.f, 0.f, 0.f};

    for (int ks = 0; ks < 6; ++ks) {
        bf16x8 b[2];
#pragma unroll
        for (int j = 0; j < 2; ++j)
            b[j] = *reinterpret_cast<const bf16x8*>(
                W2p + (((size_t)(wave + 4 * j) * 6 + ks) * 64 + lane) * 8);
        const int kb = ks * 64 + khalf;
#pragma unroll
        for (int m = 0; m < 3; ++m) {
            const int row = m * 16 + r16;
            const bf16x8 a = *reinterpret_cast<const bf16x8*>(
                Xs + row * 384 + (kb ^ ((row & 7) << 4)));
#pragma unroll
            for (int j = 0; j < 2; ++j)
                acc2[m][j] = __builtin_amdgcn_mfma_f32_16x16x32_bf16(a, b[j], acc2[m][j], 0, 0, 0);
        }
    }

    // epilogue: msg = selu(F)*a, scatter-add by dst
#pragma unroll
    for (int j = 0; j < 2; ++j) {
        const int n = (wave + 4 * j) * 16 + r16;
        const float bb = b2[n];
#pragma unroll
        for (int m = 0; m < 3; ++m)
#pragma unroll
            for (int r = 0; r < 4; ++r) {
                const int e = m * 16 + rbase + r;
                const float a_ = aa[e];
                if (a_ != 0.f)
                    atomicAdd(&dout[(size_t)edst[e] * OUTC + n],
                              selu_f(acc2[m][j][r] + bb) * a_);
            }
    }
}

// ---------------- K4: finalize (overwrite-or-sigmoid), in place ----------
__global__ __launch_bounds__(64) void k_finalize(
    float* __restrict__ dout, const float* __restrict__ met,
    const float* __restrict__ bias)
{
    const int n = blockIdx.x;
    const int lane = threadIdx.x;
    const float a0 = dout[(size_t)n * OUTC + lane];
    const float a1 = dout[(size_t)n * OUTC + 64 + lane];
    const bool ovr = __all((a0 == 0.f) && (a1 == 0.f));
    float r0, r1;
    if (ovr) {
        r0 = met[(size_t)n * DMC + lane];
        r1 = met[(size_t)n * DMC + 64 + lane];
    } else {
        r0 = 1.f / (1.f + __expf(-(a0 + bias[lane])));
        r1 = 1.f / (1.f + __expf(-(a1 + bias[64 + lane])));
    }
    dout[(size_t)n * OUTC + lane] = r0;
    dout[(size_t)n * OUTC + 64 + lane] = r1;
}

extern "C" void kernel_launch(void* const* d_in, const int* in_sizes, int n_in,
                              void* d_out, int out_size, void* d_ws, size_t ws_size,
                              hipStream_t stream)
{
    const int*   ei   = (const int*)d_in[0];
    const float* ss   = (const float*)d_in[1];
    const float* se   = (const float*)d_in[2];
    const float* ctx  = (const float*)d_in[3];
    const float* met  = (const float*)d_in[4];
    const float* Wl   = (const float*)d_in[5];
    const float* bl   = (const float*)d_in[6];
    const float* Wr   = (const float*)d_in[7];
    const float* br   = (const float*)d_in[8];
    const float* att  = (const float*)d_in[9];
    const float* W1   = (const float*)d_in[10];
    const float* b1   = (const float*)d_in[11];
    const float* W2   = (const float*)d_in[12];
    const float* b2   = (const float*)d_in[13];
    const float* bias = (const float*)d_in[14];

    u16* clb  = (u16*)d_ws;
    u16* crb  = clb  + (size_t)NN * CCH;
    u16* metb = crb  + (size_t)NN * CCH;
    u16* W1p  = metb + (size_t)NN * DMC;
    u16* W2p  = W1p  + (size_t)(CCH + DMC) * HDC;
    u16* W0p  = W2p  + (size_t)HDC * OUTC;
    float* exb = (float*)(W0p + (size_t)CCH * 512);
    float* sb  = exb + EE;

    float* dout = (float*)d_out;

    hipMemsetAsync(dout, 0, (size_t)NN * OUTC * sizeof(float), stream);
    hipMemsetAsync(sb, 0, (size_t)NN * sizeof(float), stream);

    // pack weights: W0p = [Wl | Wr] as 256x512; W1p, W2p as before
    k_pack_w<<<(CCH / 16) * (CCH / 32), 64, 0, stream>>>(Wl, W0p, CCH, CCH);
    k_pack_w<<<(CCH / 16) * (CCH / 32), 64, 0, stream>>>(Wr, W0p + (size_t)128 * 64 * 8, CCH, CCH);
    k_pack_w<<<(HDC / 16) * ((CCH + DMC) / 32), 64, 0, stream>>>(W1, W1p, CCH + DMC, HDC);
    k_pack_w<<<(OUTC / 16) * (HDC / 32), 64, 0, stream>>>(W2, W2p, HDC, OUTC);
    k_convert<<<(NN * DMC / 4 + 255) / 256, 256, 0, stream>>>(met, metb, NN * DMC);

    k_node_gemm<<<(NN + 63) / 64, 256, 0, stream>>>(ss, se, ctx, W0p, bl, br, clb, crb);
    k_edge_alpha<<<EE / 16, 256, 0, stream>>>(ei, clb, crb, metb, att, exb, sb);
    k_edge_mlp<<<(EE + ET - 1) / ET, 256, 0, stream>>>(ei, clb, crb, metb, exb, sb, W1p, b1, W2p, b2, dout);
    k_finalize<<<NN, 64, 0, stream>>>(dout, met, bias);
}

// Round 4
// 950.758 us; speedup vs baseline: 5.4119x; 1.1334x over previous
//
#include <hip/hip_runtime.h>
#include <hip/hip_bf16.h>
#include <math.h>

#define NN   100000
#define EE   1000000
#define CCH  256      // context channels
#define DMC  128      // stage_metrics channels
#define HDC  192      // hidden of final transform
#define OUTC 128      // out channels
#define ET   48       // edges per k_edge_mlp block (3 m-tiles)

typedef unsigned short u16;
using bf16x8 = __attribute__((ext_vector_type(8))) short;
using f32x4  = __attribute__((ext_vector_type(4))) float;
using u16x4  = __attribute__((ext_vector_type(4))) unsigned short;
using u16x8  = __attribute__((ext_vector_type(8))) unsigned short;

// selu via v_exp: ~6 VALU vs ~13 for expm1f path
__device__ __forceinline__ float selu_f(float x) {
    const float sc = 1.0507009873554804934193349852946f;
    const float c1 = 1.7580993408473765792727863477367f;  // sc*alpha
    const float e = __expf(x);
    return x > 0.0f ? sc * x : __builtin_fmaf(c1, e, -c1);
}
__device__ __forceinline__ u16 f2bf(float f) {   // RNE via compiler (emits cvt_pk)
    union { __hip_bfloat16 h; u16 u; } c;
    c.h = __float2bfloat16(f);
    return c.u;
}
__device__ __forceinline__ float bf2f(u16 h) {
    return __uint_as_float(((unsigned int)h) << 16);
}

// ---------------- K1: node transform as bf16 MFMA GEMM -------------------
// [64 nodes x 256] @ [256 x 512] (Wl|Wr fused). 4 waves; wave owns all 4
// m-tiles x 8 n-tiles (nt = wave+4*jj). X in LDS bf16, swizzled.
__global__ __launch_bounds__(256, 2) void k_node_gemm(
    const float* __restrict__ ss, const float* __restrict__ se,
    const float* __restrict__ ctx, const u16* __restrict__ W0p,
    const float* __restrict__ bl, const float* __restrict__ br,
    u16* __restrict__ clb, u16* __restrict__ crb)
{
    __shared__ __align__(16) char Xs[64 * 512];  // [64][256] bf16 swizzled
    const int tid = threadIdx.x;
    const int wave = tid >> 6, lane = tid & 63;
    const int node0 = blockIdx.x * 64;

    {
        const int r = lane;
        const int nd = min(node0 + r, NN - 1);
#pragma unroll
        for (int i = 0; i < 8; ++i) {
            const int c0 = wave * 64 + i * 8;
            float4 va, vb;
            {
                const int c = c0;
                if (c < 16)       va = *reinterpret_cast<const float4*>(ss + nd * 16 + c);
                else if (c < 240) va = *reinterpret_cast<const float4*>(ctx + (size_t)nd * 224 + (c - 16));
                else              va = *reinterpret_cast<const float4*>(se + nd * 16 + (c - 240));
            }
            {
                const int c = c0 + 4;
                if (c < 16)       vb = *reinterpret_cast<const float4*>(ss + nd * 16 + c);
                else if (c < 240) vb = *reinterpret_cast<const float4*>(ctx + (size_t)nd * 224 + (c - 16));
                else              vb = *reinterpret_cast<const float4*>(se + nd * 16 + (c - 240));
            }
            u16x8 v;
            v[0] = f2bf(va.x); v[1] = f2bf(va.y); v[2] = f2bf(va.z); v[3] = f2bf(va.w);
            v[4] = f2bf(vb.x); v[5] = f2bf(vb.y); v[6] = f2bf(vb.z); v[7] = f2bf(vb.w);
            *reinterpret_cast<u16x8*>(Xs + r * 512 + ((c0 * 2) ^ ((r & 7) << 4))) = v;
        }
    }
    __syncthreads();

    const int r16   = lane & 15;
    const int khalf = (lane >> 4) << 4;
    const int rbase = (lane >> 4) * 4;

    f32x4 acc[4][8];
#pragma unroll
    for (int m = 0; m < 4; ++m)
#pragma unroll
        for (int jj = 0; jj < 8; ++jj) acc[m][jj] = (f32x4){0.f, 0.f, 0.f, 0.f};

    for (int ks = 0; ks < 8; ++ks) {
        bf16x8 b[8];
#pragma unroll
        for (int jj = 0; jj < 8; ++jj)
            b[jj] = *reinterpret_cast<const bf16x8*>(
                W0p + (((size_t)(wave + 4 * jj) * 8 + ks) * 64 + lane) * 8);
        const int kb = ks * 64 + khalf;
#pragma unroll
        for (int m = 0; m < 4; ++m) {
            const int row = m * 16 + r16;
            const bf16x8 a = *reinterpret_cast<const bf16x8*>(
                Xs + row * 512 + (kb ^ ((row & 7) << 4)));
#pragma unroll
            for (int jj = 0; jj < 8; ++jj)
                acc[m][jj] = __builtin_amdgcn_mfma_f32_16x16x32_bf16(a, b[jj], acc[m][jj], 0, 0, 0);
        }
    }

#pragma unroll
    for (int jj = 0; jj < 8; ++jj) {
        const int nt = wave + 4 * jj;            // wave-uniform branch
        const bool isL = nt < 16;
        const int ncl = (isL ? nt * 16 : (nt - 16) * 16) + r16;
        const float bias = isL ? bl[ncl] : br[ncl];
        u16* base = (isL ? clb : crb) + ncl;
#pragma unroll
        for (int m = 0; m < 4; ++m)
#pragma unroll
            for (int rr = 0; rr < 4; ++rr) {
                const int node = node0 + m * 16 + rbase + rr;
                if (node < NN)
                    base[(size_t)node * CCH] = f2bf(acc[m][jj][rr] + bias);
            }
    }
}

// ---------------- K1b: fp32 -> bf16 convert (for metrics) ----------------
__global__ __launch_bounds__(256) void k_convert(
    const float* __restrict__ in, u16* __restrict__ out, int n)
{
    const int i = (blockIdx.x * 256 + threadIdx.x) * 4;
    if (i < n) {
        const float4 v = *reinterpret_cast<const float4*>(in + i);
        u16x4 o; o[0] = f2bf(v.x); o[1] = f2bf(v.y); o[2] = f2bf(v.z); o[3] = f2bf(v.w);
        *reinterpret_cast<u16x4*>(out + i) = o;
    }
}

// ---------------- K1c: pack W (KxN fp32 row-major) into MFMA B-fragments -
__global__ __launch_bounds__(64) void k_pack_w(
    const float* __restrict__ W, u16* __restrict__ out, int K, int N)
{
    const int f = blockIdx.x, lane = threadIdx.x;
    const int KS = K >> 5;
    const int nt = f / KS, ks = f - nt * KS;
    const int n = nt * 16 + (lane & 15);
    const int k0 = ks * 32 + (lane >> 4) * 8;
    u16x8 v;
#pragma unroll
    for (int j = 0; j < 8; ++j) v[j] = f2bf(W[(size_t)(k0 + j) * N + n]);
    *reinterpret_cast<u16x8*>(out + ((size_t)f * 64 + lane) * 8) = v;
}

// ---------------- K3: fused per-edge alpha + MLP + weighted scatter ------
// 48 edges/block, 4 waves. X=[selu(cr+cl)|met] built once in LDS; alpha is
// a 16-lane LDS dot on X; msg=f*ex scattered UNNORMALIZED; sb[dst]+=ex;
// finalize divides by (sb+1e-16). This deletes the separate alpha pass.
__global__ __launch_bounds__(256, 4) void k_edge_mlp(
    const int* __restrict__ ei, const u16* __restrict__ clb,
    const u16* __restrict__ crb, const u16* __restrict__ metb,
    const float* __restrict__ att, float* __restrict__ sb,
    const u16* __restrict__ W1p, const float* __restrict__ b1,
    const u16* __restrict__ W2p, const float* __restrict__ b2,
    float* __restrict__ dout)
{
    __shared__ __align__(16) char Xs[ET * 768];   // X [48][384]bf16; reused for H [48][192]
    __shared__ int esrc[ET], edst[ET];
    __shared__ float exs[ET];

    const int tid  = threadIdx.x;
    const int wave = tid >> 6;
    const int lane = tid & 63;
    const int ebase = blockIdx.x * ET;

    if (tid < ET) {
        const int e = ebase + tid;
        const bool valid = e < EE;
        esrc[tid] = valid ? ei[e] : 0;
        edst[tid] = valid ? ei[EE + e] : 0;
    }
    __syncthreads();

    // ---- build X = [selu(cr[dst]+cl[src]) | metrics[src]], bf16, swizzled
    for (int k = tid; k < ET * 48; k += 256) {
        const int t = k / 48, c = k - t * 48;     // c: group of 8 cols
        u16x8 v;
        if (c < 32) {
            const u16x8 r = *reinterpret_cast<const u16x8*>(crb + (size_t)edst[t] * CCH + c * 8);
            const u16x8 l = *reinterpret_cast<const u16x8*>(clb + (size_t)esrc[t] * CCH + c * 8);
#pragma unroll
            for (int j = 0; j < 8; ++j) v[j] = f2bf(selu_f(bf2f(r[j]) + bf2f(l[j])));
        } else {
            v = *reinterpret_cast<const u16x8*>(metb + (size_t)esrc[t] * DMC + (c - 32) * 8);
        }
        *reinterpret_cast<u16x8*>(Xs + t * 768 + ((c * 16) ^ ((t & 7) << 4))) = v;
    }
    __syncthreads();

    // ---- alpha phase: 16 lanes per edge, 3 passes (16 edges per pass)
    {
        const int li = tid & 15;
        const int eg = tid >> 4;   // 0..15
        const float4 av0 = *reinterpret_cast<const float4*>(att + li * 16);
        const float4 av1 = *reinterpret_cast<const float4*>(att + li * 16 + 4);
        const float4 av2 = *reinterpret_cast<const float4*>(att + li * 16 + 8);
        const float4 av3 = *reinterpret_cast<const float4*>(att + li * 16 + 12);
#pragma unroll
        for (int p = 0; p < 3; ++p) {
            const int e = p * 16 + eg;
            const int rb = e * 768;
            const int sw = (e & 7) << 4;
            const u16x8 x0 = *reinterpret_cast<const u16x8*>(Xs + rb + ((li * 32) ^ sw));
            const u16x8 x1 = *reinterpret_cast<const u16x8*>(Xs + rb + ((li * 32 + 16) ^ sw));
            const u16x8 xm = *reinterpret_cast<const u16x8*>(Xs + rb + ((512 + li * 16) ^ sw));
            float al = bf2f(x0[0]) * av0.x + bf2f(x0[1]) * av0.y
                     + bf2f(x0[2]) * av0.z + bf2f(x0[3]) * av0.w
                     + bf2f(x0[4]) * av1.x + bf2f(x0[5]) * av1.y
                     + bf2f(x0[6]) * av1.z + bf2f(x0[7]) * av1.w
                     + bf2f(x1[0]) * av2.x + bf2f(x1[1]) * av2.y
                     + bf2f(x1[2]) * av2.z + bf2f(x1[3]) * av2.w
                     + bf2f(x1[4]) * av3.x + bf2f(x1[5]) * av3.y
                     + bf2f(x1[6]) * av3.z + bf2f(x1[7]) * av3.w;
            unsigned ob = 0;
#pragma unroll
            for (int j = 0; j < 8; ++j) ob |= (unsigned)xm[j];
            const bool nz = (ob & 0x7fffu) != 0u;
            const unsigned long long bal = __ballot(nz);
            const bool anynz = ((bal >> ((lane >> 4) * 16)) & 0xFFFFull) != 0ull;
#pragma unroll
            for (int off = 1; off < 16; off <<= 1) al += __shfl_xor(al, off);
            float ex = 0.f;
            if (anynz && al != 0.f && (ebase + e) < EE) ex = __expf(al);
            if (li == 0) {
                exs[e] = ex;
                if (ex != 0.f) atomicAdd(&sb[edst[e]], ex);
            }
        }
    }

    const int r16   = lane & 15;
    const int khalf = (lane >> 4) << 4;
    const int rbase = (lane >> 4) * 4;

    // ---- GEMM1: H = selu(X @ W1 + b1)
    f32x4 acc[3][3];
#pragma unroll
    for (int m = 0; m < 3; ++m)
#pragma unroll
        for (int j = 0; j < 3; ++j) acc[m][j] = (f32x4){0.f, 0.f, 0.f, 0.f};

    for (int ks = 0; ks < 12; ++ks) {
        bf16x8 b[3];
#pragma unroll
        for (int j = 0; j < 3; ++j)
            b[j] = *reinterpret_cast<const bf16x8*>(
                W1p + (((size_t)(wave + 4 * j) * 12 + ks) * 64 + lane) * 8);
        const int kb = ks * 64 + khalf;
#pragma unroll
        for (int m = 0; m < 3; ++m) {
            const int row = m * 16 + r16;
            const bf16x8 a = *reinterpret_cast<const bf16x8*>(
                Xs + row * 768 + (kb ^ ((row & 7) << 4)));
#pragma unroll
            for (int j = 0; j < 3; ++j)
                acc[m][j] = __builtin_amdgcn_mfma_f32_16x16x32_bf16(a, b[j], acc[m][j], 0, 0, 0);
        }
    }
    __syncthreads();   // all X/exs reads+writes settle before overwrite with H

    // ---- write H (bf16, swizzled, row stride 384B)
#pragma unroll
    for (int j = 0; j < 3; ++j) {
        const int n = (wave + 4 * j) * 16 + r16;
        const float bb = b1[n];
#pragma unroll
        for (int m = 0; m < 3; ++m)
#pragma unroll
            for (int r = 0; r < 4; ++r) {
                const int row = m * 16 + rbase + r;
                *reinterpret_cast<u16*>(Xs + row * 384 + ((n * 2) ^ ((row & 7) << 4))) =
                    f2bf(selu_f(acc[m][j][r] + bb));
            }
    }
    __syncthreads();

    // ---- GEMM2: F = selu(H @ W2 + b2)
    f32x4 acc2[3][2];
#pragma unroll
    for (int m = 0; m < 3; ++m)
#pragma unroll
        for (int j = 0; j < 2; ++j) acc2[m][j] = (f32x4){0.f, 0.f, 0.f, 0.f};

    for (int ks = 0; ks < 6; ++ks) {
        bf16x8 b[2];
#pragma unroll
        for (int j = 0; j < 2; ++j)
            b[j] = *reinterpret_cast<const bf16x8*>(
                W2p + (((size_t)(wave + 4 * j) * 6 + ks) * 64 + lane) * 8);
        const int kb = ks * 64 + khalf;
#pragma unroll
        for (int m = 0; m < 3; ++m) {
            const int row = m * 16 + r16;
            const bf16x8 a = *reinterpret_cast<const bf16x8*>(
                Xs + row * 384 + (kb ^ ((row & 7) << 4)));
#pragma unroll
            for (int j = 0; j < 2; ++j)
                acc2[m][j] = __builtin_amdgcn_mfma_f32_16x16x32_bf16(a, b[j], acc2[m][j], 0, 0, 0);
        }
    }

    // ---- epilogue: msg = selu(F)*ex (UNNORMALIZED), scatter-add by dst
#pragma unroll
    for (int j = 0; j < 2; ++j) {
        const int n = (wave + 4 * j) * 16 + r16;
        const float bb = b2[n];
#pragma unroll
        for (int m = 0; m < 3; ++m)
#pragma unroll
            for (int r = 0; r < 4; ++r) {
                const int e = m * 16 + rbase + r;
                const float ex_ = exs[e];
                if (ex_ != 0.f)
                    atomicAdd(&dout[(size_t)edst[e] * OUTC + n],
                              selu_f(acc2[m][j][r] + bb) * ex_);
            }
    }
}

// ---------------- K4: finalize: divide by sum, overwrite-or-sigmoid ------
__global__ __launch_bounds__(64) void k_finalize(
    float* __restrict__ dout, const float* __restrict__ met,
    const float* __restrict__ bias, const float* __restrict__ sb)
{
    const int n = blockIdx.x;
    const int lane = threadIdx.x;
    const float a0 = dout[(size_t)n * OUTC + lane];
    const float a1 = dout[(size_t)n * OUTC + 64 + lane];
    const bool ovr = __all((a0 == 0.f) && (a1 == 0.f));
    float r0, r1;
    if (ovr) {
        r0 = met[(size_t)n * DMC + lane];
        r1 = met[(size_t)n * DMC + 64 + lane];
    } else {
        const float inv = 1.0f / (sb[n] + 1e-16f);
        r0 = 1.f / (1.f + __expf(-(a0 * inv + bias[lane])));
        r1 = 1.f / (1.f + __expf(-(a1 * inv + bias[64 + lane])));
    }
    dout[(size_t)n * OUTC + lane] = r0;
    dout[(size_t)n * OUTC + 64 + lane] = r1;
}

extern "C" void kernel_launch(void* const* d_in, const int* in_sizes, int n_in,
                              void* d_out, int out_size, void* d_ws, size_t ws_size,
                              hipStream_t stream)
{
    const int*   ei   = (const int*)d_in[0];
    const float* ss   = (const float*)d_in[1];
    const float* se   = (const float*)d_in[2];
    const float* ctx  = (const float*)d_in[3];
    const float* met  = (const float*)d_in[4];
    const float* Wl   = (const float*)d_in[5];
    const float* bl   = (const float*)d_in[6];
    const float* Wr   = (const float*)d_in[7];
    const float* br   = (const float*)d_in[8];
    const float* att  = (const float*)d_in[9];
    const float* W1   = (const float*)d_in[10];
    const float* b1   = (const float*)d_in[11];
    const float* W2   = (const float*)d_in[12];
    const float* b2   = (const float*)d_in[13];
    const float* bias = (const float*)d_in[14];

    u16* clb  = (u16*)d_ws;
    u16* crb  = clb  + (size_t)NN * CCH;
    u16* metb = crb  + (size_t)NN * CCH;
    u16* W1p  = metb + (size_t)NN * DMC;
    u16* W2p  = W1p  + (size_t)(CCH + DMC) * HDC;
    u16* W0p  = W2p  + (size_t)HDC * OUTC;
    float* sb = (float*)(W0p + (size_t)CCH * 512);

    float* dout = (float*)d_out;

    hipMemsetAsync(dout, 0, (size_t)NN * OUTC * sizeof(float), stream);
    hipMemsetAsync(sb, 0, (size_t)NN * sizeof(float), stream);

    // pack weights: W0p = [Wl | Wr] as 256x512; W1p, W2p as before
    k_pack_w<<<(CCH / 16) * (CCH / 32), 64, 0, stream>>>(Wl, W0p, CCH, CCH);
    k_pack_w<<<(CCH / 16) * (CCH / 32), 64, 0, stream>>>(Wr, W0p + (size_t)128 * 64 * 8, CCH, CCH);
    k_pack_w<<<(HDC / 16) * ((CCH + DMC) / 32), 64, 0, stream>>>(W1, W1p, CCH + DMC, HDC);
    k_pack_w<<<(OUTC / 16) * (HDC / 32), 64, 0, stream>>>(W2, W2p, HDC, OUTC);
    k_convert<<<(NN * DMC / 4 + 255) / 256, 256, 0, stream>>>(met, metb, NN * DMC);

    k_node_gemm<<<(NN + 63) / 64, 256, 0, stream>>>(ss, se, ctx, W0p, bl, br, clb, crb);
    k_edge_mlp<<<(EE + ET - 1) / ET, 256, 0, stream>>>(ei, clb, crb, metb, att, sb, W1p, b1, W2p, b2, dout);
    k_finalize<<<NN, 64, 0, stream>>>(dout, met, bias, sb);
}

// Round 5
// 896.633 us; speedup vs baseline: 5.7386x; 1.0604x over previous
//
#include <hip/hip_runtime.h>
#include <hip/hip_bf16.h>
#include <math.h>

#define NN   100000
#define EE   1000000
#define CCH  256      // context channels
#define DMC  128      // stage_metrics channels
#define HDC  192      // hidden of final transform
#define OUTC 128      // out channels
#define ET   32       // edges per k_edge_mlp block (2 m-tiles); EE%ET==0

typedef unsigned short u16;
using bf16x8 = __attribute__((ext_vector_type(8))) short;
using f32x4  = __attribute__((ext_vector_type(4))) float;
using u16x4  = __attribute__((ext_vector_type(4))) unsigned short;
using u16x8  = __attribute__((ext_vector_type(8))) unsigned short;

// selu via v_exp: ~6 VALU vs ~13 for expm1f path
__device__ __forceinline__ float selu_f(float x) {
    const float sc = 1.0507009873554804934193349852946f;
    const float c1 = 1.7580993408473765792727863477367f;  // sc*alpha
    const float e = __expf(x);
    return x > 0.0f ? sc * x : __builtin_fmaf(c1, e, -c1);
}
__device__ __forceinline__ u16 f2bf(float f) {   // RNE via compiler (emits cvt_pk)
    union { __hip_bfloat16 h; u16 u; } c;
    c.h = __float2bfloat16(f);
    return c.u;
}
__device__ __forceinline__ float bf2f(u16 h) {
    return __uint_as_float(((unsigned int)h) << 16);
}

// ---------------- K1: node transform as bf16 MFMA GEMM -------------------
// [64 nodes x 256] @ [256 x 512] (Wl|Wr fused). 4 waves; wave owns all 4
// m-tiles x 8 n-tiles (nt = wave+4*jj). X in LDS bf16, swizzled.
__global__ __launch_bounds__(256, 2) void k_node_gemm(
    const float* __restrict__ ss, const float* __restrict__ se,
    const float* __restrict__ ctx, const u16* __restrict__ W0p,
    const float* __restrict__ bl, const float* __restrict__ br,
    u16* __restrict__ clb, u16* __restrict__ crb)
{
    __shared__ __align__(16) char Xs[64 * 512];  // [64][256] bf16 swizzled
    const int tid = threadIdx.x;
    const int wave = tid >> 6, lane = tid & 63;
    const int node0 = blockIdx.x * 64;

    {
        const int r = lane;
        const int nd = min(node0 + r, NN - 1);
#pragma unroll
        for (int i = 0; i < 8; ++i) {
            const int c0 = wave * 64 + i * 8;
            float4 va, vb;
            {
                const int c = c0;
                if (c < 16)       va = *reinterpret_cast<const float4*>(ss + nd * 16 + c);
                else if (c < 240) va = *reinterpret_cast<const float4*>(ctx + (size_t)nd * 224 + (c - 16));
                else              va = *reinterpret_cast<const float4*>(se + nd * 16 + (c - 240));
            }
            {
                const int c = c0 + 4;
                if (c < 16)       vb = *reinterpret_cast<const float4*>(ss + nd * 16 + c);
                else if (c < 240) vb = *reinterpret_cast<const float4*>(ctx + (size_t)nd * 224 + (c - 16));
                else              vb = *reinterpret_cast<const float4*>(se + nd * 16 + (c - 240));
            }
            u16x8 v;
            v[0] = f2bf(va.x); v[1] = f2bf(va.y); v[2] = f2bf(va.z); v[3] = f2bf(va.w);
            v[4] = f2bf(vb.x); v[5] = f2bf(vb.y); v[6] = f2bf(vb.z); v[7] = f2bf(vb.w);
            *reinterpret_cast<u16x8*>(Xs + r * 512 + ((c0 * 2) ^ ((r & 7) << 4))) = v;
        }
    }
    __syncthreads();

    const int r16   = lane & 15;
    const int khalf = (lane >> 4) << 4;
    const int rbase = (lane >> 4) * 4;

    f32x4 acc[4][8];
#pragma unroll
    for (int m = 0; m < 4; ++m)
#pragma unroll
        for (int jj = 0; jj < 8; ++jj) acc[m][jj] = (f32x4){0.f, 0.f, 0.f, 0.f};

    for (int ks = 0; ks < 8; ++ks) {
        bf16x8 b[8];
#pragma unroll
        for (int jj = 0; jj < 8; ++jj)
            b[jj] = *reinterpret_cast<const bf16x8*>(
                W0p + (((size_t)(wave + 4 * jj) * 8 + ks) * 64 + lane) * 8);
        const int kb = ks * 64 + khalf;
#pragma unroll
        for (int m = 0; m < 4; ++m) {
            const int row = m * 16 + r16;
            const bf16x8 a = *reinterpret_cast<const bf16x8*>(
                Xs + row * 512 + (kb ^ ((row & 7) << 4)));
#pragma unroll
            for (int jj = 0; jj < 8; ++jj)
                acc[m][jj] = __builtin_amdgcn_mfma_f32_16x16x32_bf16(a, b[jj], acc[m][jj], 0, 0, 0);
        }
    }

#pragma unroll
    for (int jj = 0; jj < 8; ++jj) {
        const int nt = wave + 4 * jj;            // wave-uniform branch
        const bool isL = nt < 16;
        const int ncl = (isL ? nt * 16 : (nt - 16) * 16) + r16;
        const float bias = isL ? bl[ncl] : br[ncl];
        u16* base = (isL ? clb : crb) + ncl;
#pragma unroll
        for (int m = 0; m < 4; ++m)
#pragma unroll
            for (int rr = 0; rr < 4; ++rr) {
                const int node = node0 + m * 16 + rbase + rr;
                if (node < NN)
                    base[(size_t)node * CCH] = f2bf(acc[m][jj][rr] + bias);
            }
    }
}

// ---------------- K1b: fp32 -> bf16 convert (for metrics) ----------------
__global__ __launch_bounds__(256) void k_convert(
    const float* __restrict__ in, u16* __restrict__ out, int n)
{
    const int i = (blockIdx.x * 256 + threadIdx.x) * 4;
    if (i < n) {
        const float4 v = *reinterpret_cast<const float4*>(in + i);
        u16x4 o; o[0] = f2bf(v.x); o[1] = f2bf(v.y); o[2] = f2bf(v.z); o[3] = f2bf(v.w);
        *reinterpret_cast<u16x4*>(out + i) = o;
    }
}

// ---------------- K1c: pack W (KxN fp32 row-major) into MFMA B-fragments -
__global__ __launch_bounds__(64) void k_pack_w(
    const float* __restrict__ W, u16* __restrict__ out, int K, int N)
{
    const int f = blockIdx.x, lane = threadIdx.x;
    const int KS = K >> 5;
    const int nt = f / KS, ks = f - nt * KS;
    const int n = nt * 16 + (lane & 15);
    const int k0 = ks * 32 + (lane >> 4) * 8;
    u16x8 v;
#pragma unroll
    for (int j = 0; j < 8; ++j) v[j] = f2bf(W[(size_t)(k0 + j) * N + n]);
    *reinterpret_cast<u16x8*>(out + ((size_t)f * 64 + lane) * 8) = v;
}

// ---------------- K3: fused per-edge alpha + MLP + weighted scatter ------
// 32 edges/block, 4 waves, ~25KB LDS -> 6 blocks/CU (24 waves, 75% occ).
// X=[selu(cr+cl)|met] built once in LDS; alpha = 16-lane LDS dot on X;
// msg=f*ex scattered UNNORMALIZED; sb[dst]+=ex; finalize divides.
__global__ __launch_bounds__(256, 6) void k_edge_mlp(
    const int* __restrict__ ei, const u16* __restrict__ clb,
    const u16* __restrict__ crb, const u16* __restrict__ metb,
    const float* __restrict__ att, float* __restrict__ sb,
    const u16* __restrict__ W1p, const float* __restrict__ b1,
    const u16* __restrict__ W2p, const float* __restrict__ b2,
    float* __restrict__ dout)
{
    __shared__ __align__(16) char Xs[ET * 768];   // X [32][384]bf16; reused for H [32][192]
    __shared__ int esrc[ET], edst[ET];
    __shared__ float exs[ET];

    const int tid  = threadIdx.x;
    const int wave = tid >> 6;
    const int lane = tid & 63;
    const int ebase = blockIdx.x * ET;            // EE % ET == 0: no tail

    if (tid < ET) {
        const int e = ebase + tid;
        esrc[tid] = ei[e];
        edst[tid] = ei[EE + e];
    }
    __syncthreads();

    // ---- build X = [selu(cr[dst]+cl[src]) | metrics[src]], bf16, swizzled
#pragma unroll
    for (int i = 0; i < ET * 48 / 256; ++i) {
        const int k = tid + i * 256;
        const int t = k / 48, c = k - t * 48;     // c: group of 8 cols
        u16x8 v;
        if (c < 32) {
            const u16x8 r = *reinterpret_cast<const u16x8*>(crb + (size_t)edst[t] * CCH + c * 8);
            const u16x8 l = *reinterpret_cast<const u16x8*>(clb + (size_t)esrc[t] * CCH + c * 8);
#pragma unroll
            for (int j = 0; j < 8; ++j) v[j] = f2bf(selu_f(bf2f(r[j]) + bf2f(l[j])));
        } else {
            v = *reinterpret_cast<const u16x8*>(metb + (size_t)esrc[t] * DMC + (c - 32) * 8);
        }
        *reinterpret_cast<u16x8*>(Xs + t * 768 + ((c * 16) ^ ((t & 7) << 4))) = v;
    }
    __syncthreads();

    // ---- alpha phase: 16 lanes per edge, 2 passes (16 edges per pass)
    {
        const int li = tid & 15;
        const int eg = tid >> 4;   // 0..15
        const float4 av0 = *reinterpret_cast<const float4*>(att + li * 16);
        const float4 av1 = *reinterpret_cast<const float4*>(att + li * 16 + 4);
        const float4 av2 = *reinterpret_cast<const float4*>(att + li * 16 + 8);
        const float4 av3 = *reinterpret_cast<const float4*>(att + li * 16 + 12);
#pragma unroll
        for (int p = 0; p < ET / 16; ++p) {
            const int e = p * 16 + eg;
            const int rb = e * 768;
            const int sw = (e & 7) << 4;
            const u16x8 x0 = *reinterpret_cast<const u16x8*>(Xs + rb + ((li * 32) ^ sw));
            const u16x8 x1 = *reinterpret_cast<const u16x8*>(Xs + rb + ((li * 32 + 16) ^ sw));
            const u16x8 xm = *reinterpret_cast<const u16x8*>(Xs + rb + ((512 + li * 16) ^ sw));
            float al = bf2f(x0[0]) * av0.x + bf2f(x0[1]) * av0.y
                     + bf2f(x0[2]) * av0.z + bf2f(x0[3]) * av0.w
                     + bf2f(x0[4]) * av1.x + bf2f(x0[5]) * av1.y
                     + bf2f(x0[6]) * av1.z + bf2f(x0[7]) * av1.w
                     + bf2f(x1[0]) * av2.x + bf2f(x1[1]) * av2.y
                     + bf2f(x1[2]) * av2.z + bf2f(x1[3]) * av2.w
                     + bf2f(x1[4]) * av3.x + bf2f(x1[5]) * av3.y
                     + bf2f(x1[6]) * av3.z + bf2f(x1[7]) * av3.w;
            unsigned ob = 0;
#pragma unroll
            for (int j = 0; j < 8; ++j) ob |= (unsigned)xm[j];
            const bool nz = (ob & 0x7fffu) != 0u;
            const unsigned long long bal = __ballot(nz);
            const bool anynz = ((bal >> ((lane >> 4) * 16)) & 0xFFFFull) != 0ull;
#pragma unroll
            for (int off = 1; off < 16; off <<= 1) al += __shfl_xor(al, off);
            float ex = 0.f;
            if (anynz && al != 0.f) ex = __expf(al);
            if (li == 0) {
                exs[e] = ex;
                if (ex != 0.f) atomicAdd(&sb[edst[e]], ex);
            }
        }
    }

    const int r16   = lane & 15;
    const int khalf = (lane >> 4) << 4;
    const int rbase = (lane >> 4) * 4;

    // ---- GEMM1: H = selu(X @ W1 + b1); wave owns 2 m x 3 n tiles
    f32x4 acc[2][3];
#pragma unroll
    for (int m = 0; m < 2; ++m)
#pragma unroll
        for (int j = 0; j < 3; ++j) acc[m][j] = (f32x4){0.f, 0.f, 0.f, 0.f};

    for (int ks = 0; ks < 12; ++ks) {
        bf16x8 b[3];
#pragma unroll
        for (int j = 0; j < 3; ++j)
            b[j] = *reinterpret_cast<const bf16x8*>(
                W1p + (((size_t)(wave + 4 * j) * 12 + ks) * 64 + lane) * 8);
        const int kb = ks * 64 + khalf;
#pragma unroll
        for (int m = 0; m < 2; ++m) {
            const int row = m * 16 + r16;
            const bf16x8 a = *reinterpret_cast<const bf16x8*>(
                Xs + row * 768 + (kb ^ ((row & 7) << 4)));
#pragma unroll
            for (int j = 0; j < 3; ++j)
                acc[m][j] = __builtin_amdgcn_mfma_f32_16x16x32_bf16(a, b[j], acc[m][j], 0, 0, 0);
        }
    }
    __syncthreads();   // all X/exs reads+writes settle before overwrite with H

    // ---- write H (bf16, swizzled, row stride 384B)
#pragma unroll
    for (int j = 0; j < 3; ++j) {
        const int n = (wave + 4 * j) * 16 + r16;
        const float bb = b1[n];
#pragma unroll
        for (int m = 0; m < 2; ++m)
#pragma unroll
            for (int r = 0; r < 4; ++r) {
                const int row = m * 16 + rbase + r;
                *reinterpret_cast<u16*>(Xs + row * 384 + ((n * 2) ^ ((row & 7) << 4))) =
                    f2bf(selu_f(acc[m][j][r] + bb));
            }
    }
    __syncthreads();

    // ---- GEMM2: F = selu(H @ W2 + b2); wave owns 2 m x 2 n tiles
    f32x4 acc2[2][2];
#pragma unroll
    for (int m = 0; m < 2; ++m)
#pragma unroll
        for (int j = 0; j < 2; ++j) acc2[m][j] = (f32x4){0.f, 0.f, 0.f, 0.f};

    for (int ks = 0; ks < 6; ++ks) {
        bf16x8 b[2];
#pragma unroll
        for (int j = 0; j < 2; ++j)
            b[j] = *reinterpret_cast<const bf16x8*>(
                W2p + (((size_t)(wave + 4 * j) * 6 + ks) * 64 + lane) * 8);
        const int kb = ks * 64 + khalf;
#pragma unroll
        for (int m = 0; m < 2; ++m) {
            const int row = m * 16 + r16;
            const bf16x8 a = *reinterpret_cast<const bf16x8*>(
                Xs + row * 384 + (kb ^ ((row & 7) << 4)));
#pragma unroll
            for (int j = 0; j < 2; ++j)
                acc2[m][j] = __builtin_amdgcn_mfma_f32_16x16x32_bf16(a, b[j], acc2[m][j], 0, 0, 0);
        }
    }

    // ---- epilogue: msg = selu(F)*ex (UNNORMALIZED), scatter-add by dst
#pragma unroll
    for (int j = 0; j < 2; ++j) {
        const int n = (wave + 4 * j) * 16 + r16;
        const float bb = b2[n];
#pragma unroll
        for (int m = 0; m < 2; ++m)
#pragma unroll
            for (int r = 0; r < 4; ++r) {
                const int e = m * 16 + rbase + r;
                const float ex_ = exs[e];
                if (ex_ != 0.f)
                    atomicAdd(&dout[(size_t)edst[e] * OUTC + n],
                              selu_f(acc2[m][j][r] + bb) * ex_);
            }
    }
}

// ---------------- K4: finalize: divide by sum, overwrite-or-sigmoid ------
__global__ __launch_bounds__(64) void k_finalize(
    float* __restrict__ dout, const float* __restrict__ met,
    const float* __restrict__ bias, const float* __restrict__ sb)
{
    const int n = blockIdx.x;
    const int lane = threadIdx.x;
    const float a0 = dout[(size_t)n * OUTC + lane];
    const float a1 = dout[(size_t)n * OUTC + 64 + lane];
    const bool ovr = __all((a0 == 0.f) && (a1 == 0.f));
    float r0, r1;
    if (ovr) {
        r0 = met[(size_t)n * DMC + lane];
        r1 = met[(size_t)n * DMC + 64 + lane];
    } else {
        const float inv = 1.0f / (sb[n] + 1e-16f);
        r0 = 1.f / (1.f + __expf(-(a0 * inv + bias[lane])));
        r1 = 1.f / (1.f + __expf(-(a1 * inv + bias[64 + lane])));
    }
    dout[(size_t)n * OUTC + lane] = r0;
    dout[(size_t)n * OUTC + 64 + lane] = r1;
}

extern "C" void kernel_launch(void* const* d_in, const int* in_sizes, int n_in,
                              void* d_out, int out_size, void* d_ws, size_t ws_size,
                              hipStream_t stream)
{
    const int*   ei   = (const int*)d_in[0];
    const float* ss   = (const float*)d_in[1];
    const float* se   = (const float*)d_in[2];
    const float* ctx  = (const float*)d_in[3];
    const float* met  = (const float*)d_in[4];
    const float* Wl   = (const float*)d_in[5];
    const float* bl   = (const float*)d_in[6];
    const float* Wr   = (const float*)d_in[7];
    const float* br   = (const float*)d_in[8];
    const float* att  = (const float*)d_in[9];
    const float* W1   = (const float*)d_in[10];
    const float* b1   = (const float*)d_in[11];
    const float* W2   = (const float*)d_in[12];
    const float* b2   = (const float*)d_in[13];
    const float* bias = (const float*)d_in[14];

    u16* clb  = (u16*)d_ws;
    u16* crb  = clb  + (size_t)NN * CCH;
    u16* metb = crb  + (size_t)NN * CCH;
    u16* W1p  = metb + (size_t)NN * DMC;
    u16* W2p  = W1p  + (size_t)(CCH + DMC) * HDC;
    u16* W0p  = W2p  + (size_t)HDC * OUTC;
    float* sb = (float*)(W0p + (size_t)CCH * 512);

    float* dout = (float*)d_out;

    hipMemsetAsync(dout, 0, (size_t)NN * OUTC * sizeof(float), stream);
    hipMemsetAsync(sb, 0, (size_t)NN * sizeof(float), stream);

    // pack weights: W0p = [Wl | Wr] as 256x512; W1p, W2p as before
    k_pack_w<<<(CCH / 16) * (CCH / 32), 64, 0, stream>>>(Wl, W0p, CCH, CCH);
    k_pack_w<<<(CCH / 16) * (CCH / 32), 64, 0, stream>>>(Wr, W0p + (size_t)128 * 64 * 8, CCH, CCH);
    k_pack_w<<<(HDC / 16) * ((CCH + DMC) / 32), 64, 0, stream>>>(W1, W1p, CCH + DMC, HDC);
    k_pack_w<<<(OUTC / 16) * (HDC / 32), 64, 0, stream>>>(W2, W2p, HDC, OUTC);
    k_convert<<<(NN * DMC / 4 + 255) / 256, 256, 0, stream>>>(met, metb, NN * DMC);

    k_node_gemm<<<(NN + 63) / 64, 256, 0, stream>>>(ss, se, ctx, W0p, bl, br, clb, crb);
    k_edge_mlp<<<EE / ET, 256, 0, stream>>>(ei, clb, crb, metb, att, sb, W1p, b1, W2p, b2, dout);
    k_finalize<<<NN, 64, 0, stream>>>(dout, met, bias, sb);
}